// Round 1
// baseline (5217.584 us; speedup 1.0000x reference)
//
#include <hip/hip_runtime.h>
#include <hip/hip_bf16.h>

#define DEV __device__ __forceinline__

// ---------- sentinel: ws too small / input-shape mismatch ----------
__global__ void sentinel_k(float* out) {
  out[0] = 1000.0f;
}

__global__ __launch_bounds__(256) void zero_k(double* __restrict__ p, int n) {
  int i = blockIdx.x * 256 + threadIdx.x;
  if (i < n) p[i] = 0.0;
}

// ---------- FPS with exact spatial pruning (QuickFPS-style, bit-exact) ----------
// Semantics identical to reference _fps: fp32 distances in np op order
// ((dx*dx+dy*dy)+dz*dz), fmin chain, argmax with first-(original)-index ties.
// Groups of PPG spatially-sorted points per thread; a group is skipped in an
// iteration only when provably no dist can change (conservative fp64 bound).
template<int PPG, int NPT, int NPTS, int STRIDE>
__global__ __launch_bounds__(256) void fps_quick_k(const float* __restrict__ pts,
                                                   float* __restrict__ out_xyz,
                                                   float* __restrict__ out_f) {
  constexpr int T = 256;
  constexpr int NW = T / 64;           // 4 waves
  static_assert(NPTS == T * PPG, "one group per thread");
  const int b = blockIdx.x, t = threadIdx.x;
  const int lane = t & 63, wv = t >> 6;

  __shared__ int perm[NPTS];           // sorted-pos -> original index
  __shared__ int hist[512];
  __shared__ int base_[512];
  __shared__ int wsum[NW];
  __shared__ unsigned long long wkeyL[2][NW];
  __shared__ float4 wc4[2][NW];

  const float* Pb = pts + (size_t)b * NPTS * STRIDE;

  // ---- phase 0: counting sort by 8x8x8 cell (order within cell arbitrary;
  //      affects only grouping quality, never values/selection) ----
  for (int i = t; i < 512; i += T) hist[i] = 0;
  __syncthreads();
  int myCell[PPG];
  for (int j = 0; j < PPG; ++j) {
    int g = t * PPG + j;
    float x = Pb[(size_t)g * STRIDE];
    float y = Pb[(size_t)g * STRIDE + 1];
    float z = Pb[(size_t)g * STRIDE + 2];
    int ix = (int)(x * 8.0f); ix = ix < 0 ? 0 : (ix > 7 ? 7 : ix);
    int iy = (int)(y * 8.0f); iy = iy < 0 ? 0 : (iy > 7 ? 7 : iy);
    int iz = (int)(z * 8.0f); iz = iz < 0 ? 0 : (iz > 7 ? 7 : iz);
    int cell = (ix << 6) | (iy << 3) | iz;
    myCell[j] = cell;
    atomicAdd(&hist[cell], 1);
  }
  __syncthreads();
  {  // exclusive scan of 512 bins (2 per thread)
    int h0 = hist[2 * t], h1 = hist[2 * t + 1];
    int s2 = h0 + h1;
    int inc = s2;
    for (int d = 1; d < 64; d <<= 1) {
      int u = __shfl_up(inc, d);
      if (lane >= d) inc += u;
    }
    if (lane == 63) wsum[wv] = inc;
    __syncthreads();
    int off = 0;
#pragma unroll
    for (int w = 0; w < NW; ++w) if (w < wv) off += wsum[w];
    int excl = off + inc - s2;
    base_[2 * t] = excl;
    base_[2 * t + 1] = excl + h0;
  }
  __syncthreads();
  for (int j = 0; j < PPG; ++j) {
    int g = t * PPG + j;
    int slot = atomicAdd(&base_[myCell[j]], 1);
    perm[slot] = g;
  }
  __syncthreads();

  // ---- phase 1: load my group (exact fp32 input values), build bound ----
  float px[PPG], py[PPG], pz[PPG], dist[PPG];
  float mnx = 1e30f, mny = 1e30f, mnz = 1e30f;
  float mxx = -1e30f, mxy = -1e30f, mxz = -1e30f;
  for (int j = 0; j < PPG; ++j) {
    int g = perm[t * PPG + j];
    float x = Pb[(size_t)g * STRIDE];
    float y = Pb[(size_t)g * STRIDE + 1];
    float z = Pb[(size_t)g * STRIDE + 2];
    px[j] = x; py[j] = y; pz[j] = z; dist[j] = 1e10f;
    mnx = fminf(mnx, x); mxx = fmaxf(mxx, x);
    mny = fminf(mny, y); mxy = fmaxf(mxy, y);
    mnz = fminf(mnz, z); mxz = fmaxf(mxz, z);
  }
  double bcx = 0.5 * ((double)mnx + (double)mxx);
  double bcy = 0.5 * ((double)mny + (double)mxy);
  double bcz = 0.5 * ((double)mnz + (double)mxz);
  double r2m = 0.0;
  for (int j = 0; j < PPG; ++j) {
    double dx = (double)px[j] - bcx, dy = (double)py[j] - bcy, dz = (double)pz[j] - bcz;
    double dd = fma(dx, dx, fma(dy, dy, dz * dz));
    r2m = fmax(r2m, dd);
  }
  const double r = sqrt(r2m) * (1.0 + 1e-12) + 1e-300;   // upper bound of group radius

  // ---- initial centroid = original point 0; emit idx[0] ----
  if (t == 0) {
    float x0 = Pb[0], y0 = Pb[1], z0 = Pb[2];
    wc4[1][0] = make_float4(x0, y0, z0, 0.0f);
    size_t o = (size_t)b * NPT * 3;
    out_xyz[o] = x0; out_xyz[o + 1] = y0; out_xyz[o + 2] = z0;
    if (out_f) { out_f[o] = x0; out_f[o + 1] = y0; out_f[o + 2] = z0; }
  }
  __syncthreads();
  float ccx = wc4[1][0].x, ccy = wc4[1][0].y, ccz = wc4[1][0].z;

  unsigned long long gkey = 0;          // (dist_bits<<32) | (0xFFFFFFFF - origidx)
  float gbx = 0.0f, gby = 0.0f, gbz = 0.0f;
  double rs2 = 1e300;                   // forces update at s=0 (dist=1e10 everywhere)

  for (int s = 0; s < NPT - 1; ++s) {
    const int p = s & 1;
    // conservative skip test: skip only if every member provably satisfies
    // d32(c,point) >= dist[point]; margins (2e-6 on gmax, 1e-12 on r) dominate
    // all fp32 (<=~3e-7 rel) and fp64 rounding -> skipping never changes values.
    double dxc = (double)ccx - bcx, dyc = (double)ccy - bcy, dzc = (double)ccz - bcz;
    double tD = fma(dxc, dxc, fma(dyc, dyc, dzc * dzc));
    if (tD < rs2) {
      unsigned long long nk = 0;
      float nbx = 0.0f, nby = 0.0f, nbz = 0.0f;
      {
#pragma clang fp contract(off)
        for (int j = 0; j < PPG; ++j) {
          float dx = px[j] - ccx, dy = py[j] - ccy, dz = pz[j] - ccz;
          float d = (dx * dx + dy * dy) + dz * dz;     // exact np order, no FMA
          float dj = fminf(dist[j], d);
          dist[j] = dj;
          int g = perm[t * PPG + j];
          unsigned long long kj = ((unsigned long long)__float_as_uint(dj) << 32)
                                | (unsigned long long)(0xFFFFFFFFu - (unsigned)g);
          if (kj > nk) { nk = kj; nbx = px[j]; nby = py[j]; nbz = pz[j]; }
        }
      }
      gkey = nk; gbx = nbx; gby = nby; gbz = nbz;
      float gmaxf = __uint_as_float((unsigned)(gkey >> 32));
      double sg = sqrt((double)gmaxf * 1.000002 + 1e-300);
      double rr = r + sg;
      rs2 = rr * rr;
    }

    // wave max over 64-bit keys (keys are globally unique: distinct origidx)
    unsigned long long wk = gkey;
#define STEP64(ctrl) { \
    int lo_ = (int)(unsigned)wk, hi_ = (int)(unsigned)(wk >> 32); \
    int slo_ = __builtin_amdgcn_update_dpp(lo_, lo_, ctrl, 0xf, 0xf, false); \
    int shi_ = __builtin_amdgcn_update_dpp(hi_, hi_, ctrl, 0xf, 0xf, false); \
    unsigned long long o_ = ((unsigned long long)(unsigned)shi_ << 32) | (unsigned)slo_; \
    if (o_ > wk) wk = o_; }
    STEP64(0x111)  // row_shr:1
    STEP64(0x112)  // row_shr:2
    STEP64(0x114)  // row_shr:4
    STEP64(0x118)  // row_shr:8
    STEP64(0x142)  // row_bcast:15
    STEP64(0x143)  // row_bcast:31
#undef STEP64
    unsigned wlo = (unsigned)__builtin_amdgcn_readlane((int)(unsigned)wk, 63);
    unsigned whi = (unsigned)__builtin_amdgcn_readlane((int)(unsigned)(wk >> 32), 63);
    unsigned long long wmaxk = ((unsigned long long)whi << 32) | wlo;
    if (gkey == wmaxk) {               // exactly one lane per wave
      wkeyL[p][wv] = gkey;
      wc4[p][wv] = make_float4(gbx, gby, gbz, 0.0f);
    }
    __syncthreads();
    // block select over 4 wave winners (tree; coords ride along)
    unsigned long long k0 = wkeyL[p][0], k1 = wkeyL[p][1];
    unsigned long long k2 = wkeyL[p][2], k3 = wkeyL[p][3];
    float4 c0 = wc4[p][0], c1 = wc4[p][1], c2 = wc4[p][2], c3 = wc4[p][3];
    if (k1 > k0) { k0 = k1; c0 = c1; }
    if (k3 > k2) { k2 = k3; c2 = c3; }
    if (k2 > k0) { k0 = k2; c0 = c2; }
    ccx = c0.x; ccy = c0.y; ccz = c0.z;
    if (t == 0) {
      size_t o = ((size_t)b * NPT + s + 1) * 3;
      out_xyz[o] = ccx; out_xyz[o + 1] = ccy; out_xyz[o + 2] = ccz;
      if (out_f) { out_f[o] = ccx; out_f[o + 1] = ccy; out_f[o + 2] = ccz; }
    }
  }
}

// ---------- layer-1 (fp64 compute, fp32 inputs): ball (first 32 asc) + conv ----------
template<bool APPLY>
__global__ __launch_bounds__(256) void ball1_k(
    const float* __restrict__ xyz, const float* __restrict__ l1xyz,
    const float* __restrict__ w1, const float* __restrict__ b1,
    const double* __restrict__ A1, const double* __restrict__ B1,
    float* __restrict__ l1pts,
    double* __restrict__ S1R, double* __restrict__ S2R) {
  const int blk = blockIdx.x;
  const int b = blk >> 11, s = blk & 2047;
  const int t = threadIdx.x;
  __shared__ double w1s[768];
  __shared__ double b1s[128];
  __shared__ unsigned long long wm[4];
  __shared__ int lst[32];
  __shared__ double fls[32][6];
  __shared__ double red0[128], red1[128];

  for (int i = t; i < 768; i += 256) w1s[i] = (double)w1[i];
  if (t < 128) b1s[t] = (double)b1[t];

  const float* xb = xyz + (size_t)b * 8192 * 6;
  size_t co = ((size_t)b * 2048 + s) * 3;
  double cx = (double)l1xyz[co], cy = (double)l1xyz[co+1], cz = (double)l1xyz[co+2];

  const double R2 = 0.0025 * 0.0025;
  int cnt = 0;
  const int wvv = t >> 6, lane = t & 63;
  {
#pragma clang fp contract(off)
    double cs2 = (cx*cx + cy*cy) + cz*cz;
    for (int chunk = 0; chunk < 32 && cnt < 32; ++chunk) {
      int g = chunk * 256 + t;
      double x = (double)xb[(size_t)g*6];
      double y = (double)xb[(size_t)g*6+1];
      double z = (double)xb[(size_t)g*6+2];
      double pn2 = (x*x + y*y) + z*z;
      double dot = (cx*x + cy*y) + cz*z;
      double dsq = (cs2 + pn2) - 2.0 * dot;    // exact ref formula/order
      bool pred = !(dsq > R2);
      unsigned long long m = __ballot(pred);
      if (lane == 0) wm[wvv] = m;
      __syncthreads();
      int pre = 0, tot = 0;
      for (int w = 0; w < 4; ++w) {
        int c = __popcll(wm[w]);
        if (w < wvv) pre += c;
        tot += c;
      }
      if (pred) {
        int rank = cnt + pre + __popcll(m & ((1ull << lane) - 1ull));
        if (rank < 32) lst[rank] = g;
      }
      cnt += tot;
      __syncthreads();
    }
  }
  int cc = cnt < 32 ? cnt : 32;
  if (t >= cc && t < 32) lst[t] = lst[0];   // pad with first (center in own ball)
  __syncthreads();
  if (t < 32) {
    int j = lst[t];
    fls[t][0] = (double)xb[(size_t)j*6]   - cx;
    fls[t][1] = (double)xb[(size_t)j*6+1] - cy;
    fls[t][2] = (double)xb[(size_t)j*6+2] - cz;
    fls[t][3] = (double)xb[(size_t)j*6+3];
    fls[t][4] = (double)xb[(size_t)j*6+4];
    fls[t][5] = (double)xb[(size_t)j*6+5];
  }
  __syncthreads();
  const int d = t & 127, kh = t >> 7;
  if (APPLY) {
    double a = A1[d], bb = B1[d];
    double vmax = -1e300;
    for (int k = kh; k < 32; k += 2) {
      double h = b1s[d];
#pragma unroll
      for (int c = 0; c < 6; ++c) h = fma(fls[k][c], w1s[c*128 + d], h);
      vmax = fmax(vmax, fma(a, h, bb));
    }
    if (kh == 1) red0[d] = vmax;
    __syncthreads();
    if (kh == 0) {
      double v = fmax(vmax, red0[d]);
      l1pts[((size_t)b * 2048 + s) * 128 + d] = (float)fmax(v, 0.0);
    }
  } else {
    double p1 = 0.0, p2 = 0.0;
    for (int k = kh; k < 32; k += 2) {
      double h = b1s[d];
#pragma unroll
      for (int c = 0; c < 6; ++c) h = fma(fls[k][c], w1s[c*128 + d], h);
      p1 += h; p2 = fma(h, h, p2);
    }
    if (kh == 1) { red0[d] = p1; red1[d] = p2; }
    __syncthreads();
    if (kh == 0) {
      int rep = blk & 7;
      atomicAdd(&S1R[(size_t)rep * 128 + d], p1 + red0[d]);
      atomicAdd(&S2R[(size_t)rep * 128 + d], p2 + red1[d]);
    }
  }
}

// ---------- BN finalize (fp64): A=g/sqrt(var+eps), B=be-mu*A ----------
__global__ __launch_bounds__(256) void bn_finalize(const double* __restrict__ S1,
                                                   const double* __restrict__ S2,
                                                   int nrep, int D, double invN,
                                                   const float* __restrict__ g,
                                                   const float* __restrict__ be,
                                                   double* __restrict__ A, double* __restrict__ Bc) {
  int d = blockIdx.x * 256 + threadIdx.x;
  if (d >= D) return;
  double s1 = 0.0, s2 = 0.0;
  for (int r = 0; r < nrep; ++r) {
    s1 += S1[(size_t)r * D + d];
    s2 += S2[(size_t)r * D + d];
  }
  double mu = s1 * invN;
  double var = s2 * invN - mu * mu;
  double a = (double)g[d] / sqrt(var + 1e-5);
  A[d]  = a;
  Bc[d] = (double)be[d] - mu * a;
}

// ---------- layer-2 (fp64): ball (first 16 asc) + conv(131->693); stats / apply ----------
template<bool APPLY>
__global__ __launch_bounds__(256) void ball2_k(
    const float* __restrict__ l1xyz, const float* __restrict__ l1pts,
    const float* __restrict__ l2xyz,
    const float* __restrict__ w2, const float* __restrict__ b2,
    const double* __restrict__ A2, const double* __restrict__ B2,
    float* __restrict__ outp,
    double* __restrict__ T1R, double* __restrict__ T2R) {
  const int blk = blockIdx.x;
  const int b = blk >> 8, s = blk & 255;
  const int t = threadIdx.x;
  __shared__ double fT[131][16];
  __shared__ unsigned long long wm[4];
  __shared__ int lst[16];
  const float* Pb = l1xyz + (size_t)b * 2048 * 3;
  size_t co = ((size_t)b * 256 + s) * 3;
  double cx = (double)l2xyz[co], cy = (double)l2xyz[co+1], cz = (double)l2xyz[co+2];
  const double R2 = 0.005 * 0.005;
  int cnt = 0;
  const int wvv = t >> 6, lane = t & 63;
  {
#pragma clang fp contract(off)
    double cs2 = (cx*cx + cy*cy) + cz*cz;
    for (int chunk = 0; chunk < 8 && cnt < 16; ++chunk) {
      int g = chunk * 256 + t;
      double x = (double)Pb[(size_t)g*3];
      double y = (double)Pb[(size_t)g*3+1];
      double z = (double)Pb[(size_t)g*3+2];
      double pn2 = (x*x + y*y) + z*z;
      double dot = (cx*x + cy*y) + cz*z;
      double dsq = (cs2 + pn2) - 2.0 * dot;
      bool pred = !(dsq > R2);
      unsigned long long m = __ballot(pred);
      if (lane == 0) wm[wvv] = m;
      __syncthreads();
      int pre = 0, tot = 0;
      for (int w = 0; w < 4; ++w) {
        int c = __popcll(wm[w]);
        if (w < wvv) pre += c;
        tot += c;
      }
      if (pred) {
        int rank = cnt + pre + __popcll(m & ((1ull << lane) - 1ull));
        if (rank < 16) lst[rank] = g;
      }
      cnt += tot;
      __syncthreads();
    }
  }
  int cc = cnt < 16 ? cnt : 16;
  if (t >= cc && t < 16) lst[t] = lst[0];
  __syncthreads();
  for (int i = t; i < 16 * 131; i += 256) {
    int k = i & 15, c = i >> 4;
    int j = lst[k];
    double v;
    if (c == 0)      v = (double)Pb[(size_t)j*3]   - cx;
    else if (c == 1) v = (double)Pb[(size_t)j*3+1] - cy;
    else if (c == 2) v = (double)Pb[(size_t)j*3+2] - cz;
    else             v = (double)l1pts[((size_t)b*2048 + j)*128 + (c-3)];
    fT[c][k] = v;
  }
  __syncthreads();
  const int rep = blk & 7;
  for (int dd = 0; dd < 3; ++dd) {
    int d = t + dd * 256;
    if (d >= 693) break;
    double acc[16];
    double bv = (double)b2[d];
#pragma unroll
    for (int k = 0; k < 16; ++k) acc[k] = bv;
    for (int c = 0; c < 131; ++c) {
      double wv2 = (double)w2[(size_t)c * 693 + d];
#pragma unroll
      for (int k = 0; k < 16; ++k) acc[k] = fma(fT[c][k], wv2, acc[k]);
    }
    if (APPLY) {
      double a = A2[d], bb = B2[d];
      double vmax = -1e300;
#pragma unroll
      for (int k = 0; k < 16; ++k) vmax = fmax(vmax, fma(a, acc[k], bb));
      outp[((size_t)b * 256 + s) * 693 + d] = (float)fmax(vmax, 0.0);
    } else {
      double p1 = 0.0, p2 = 0.0;
#pragma unroll
      for (int k = 0; k < 16; ++k) { p1 += acc[k]; p2 = fma(acc[k], acc[k], p2); }
      atomicAdd(&T1R[(size_t)rep * 693 + d], p1);
      atomicAdd(&T2R[(size_t)rep * 693 + d], p2);
    }
  }
}

extern "C" void kernel_launch(void* const* d_in, const int* in_sizes, int n_in,
                              void* d_out, int out_size, void* d_ws, size_t ws_size,
                              hipStream_t stream) {
  (void)out_size;
  float* out = (float*)d_out;   // fp32 outputs (reference returns float32)

  const int want[9] = {196608, 768, 128, 128, 128, 90783, 693, 693, 693};
  bool ok = (n_in == 9);
  for (int i = 0; ok && i < 9; ++i) ok = (in_sizes[i] == want[i]);
  const size_t REQ = 4600000;   // footprint ~4.42 MB
  if (!ok || ws_size < REQ) {
    sentinel_k<<<1, 1, 0, stream>>>(out);
    return;
  }

  const float* xyz = (const float*)d_in[0];
  const float* w1  = (const float*)d_in[1];
  const float* b1  = (const float*)d_in[2];
  const float* g1  = (const float*)d_in[3];
  const float* be1 = (const float*)d_in[4];
  const float* w2  = (const float*)d_in[5];
  const float* b2  = (const float*)d_in[6];
  const float* g2  = (const float*)d_in[7];
  const float* be2 = (const float*)d_in[8];

  // ---- workspace carve (doubles first) ----
  double* S1R = (double*)d_ws;            // 8*128 = 1024
  double* S2R = S1R + 1024;               // 1024
  double* T1R = S2R + 1024;               // 8*693 = 5544
  double* T2R = T1R + 5544;               // 5544
  double* A1  = T2R + 5544;               // 128
  double* B1  = A1 + 128;                 // 128
  double* A2  = B1 + 128;                 // 693
  double* B2  = A2 + 693;                 // 693
  float* l1xyz = (float*)(B2 + 693);      // 4*2048*3 = 24576 f
  float* l2xyz = l1xyz + 24576;           // 4*256*3  = 3072 f
  float* l1pts = l2xyz + 3072;            // 4*2048*128 = 4 MB

  zero_k<<<52, 256, 0, stream>>>(S1R, 13136);

  // FPS in fp32 with exact spatial pruning (selections bit-identical to the
  // dense scan; skip test is provably conservative).
  fps_quick_k<32, 2048, 8192, 6><<<4, 256, 0, stream>>>(xyz, l1xyz, nullptr);
  fps_quick_k<8, 256, 2048, 3><<<4, 256, 0, stream>>>(l1xyz, l2xyz, out);

  ball1_k<false><<<8192, 256, 0, stream>>>(xyz, l1xyz, w1, b1, nullptr, nullptr,
                                           nullptr, S1R, S2R);
  bn_finalize<<<1, 256, 0, stream>>>(S1R, S2R, 8, 128, 1.0 / (8192.0 * 32.0), g1, be1, A1, B1);
  ball1_k<true><<<8192, 256, 0, stream>>>(xyz, l1xyz, w1, b1, A1, B1,
                                          l1pts, S1R, S2R);

  ball2_k<false><<<1024, 256, 0, stream>>>(l1xyz, l1pts, l2xyz, w2, b2, nullptr, nullptr,
                                           nullptr, T1R, T2R);
  bn_finalize<<<3, 256, 0, stream>>>(T1R, T2R, 8, 693, 1.0 / (1024.0 * 16.0), g2, be2, A2, B2);
  ball2_k<true><<<1024, 256, 0, stream>>>(l1xyz, l1pts, l2xyz, w2, b2, A2, B2,
                                          out + 3072, T1R, T2R);
}

// Round 2
// 4544.785 us; speedup vs baseline: 1.1480x; 1.1480x over previous
//
#include <hip/hip_runtime.h>
#include <hip/hip_bf16.h>

#define DEV __device__ __forceinline__

// ---------- sentinel: ws too small / input-shape mismatch ----------
__global__ void sentinel_k(float* out) {
  out[0] = 1000.0f;
}

__global__ __launch_bounds__(256) void zero_k(double* __restrict__ p, int n) {
  int i = blockIdx.x * 256 + threadIdx.x;
  if (i < n) p[i] = 0.0;
}

// ---------- FPS with exact spatial pruning (QuickFPS-style, bit-exact) ----------
// Semantics identical to reference _fps: fp32 distances in np op order
// ((dx*dx+dy*dy)+dz*dz), fmin chain, argmax with first-(original)-index ties
// via 64-bit packed keys. A thread's group is rescanned only when the fp64
// conservative bound says some dist could change; margins (2e-6, 1e-12)
// dominate all fp32/fp64 rounding, so skips never alter any value.
// 512 threads (8 waves); Morton-ordered cells => wave w owns one 4x4x4 octant.
template<int PPG, int NPT, int NPTS, int STRIDE>
__global__ __launch_bounds__(512) void fps_quick_k(const float* __restrict__ pts,
                                                   float* __restrict__ out_xyz,
                                                   float* __restrict__ out_f) {
  constexpr int T = 512;
  constexpr int NW = T / 64;           // 8 waves
  static_assert(NPTS == T * PPG, "one group per thread");
  const int b = blockIdx.x, t = threadIdx.x;
  const int lane = t & 63, wv = t >> 6;

  __shared__ int perm[NPTS];           // sorted-pos -> original index
  __shared__ int hist[512];
  __shared__ int base_[512];
  __shared__ int wsum[NW];
  __shared__ unsigned long long wkeyL[2][NW];
  __shared__ float4 wc4[2][NW];

  const float* Pb = pts + (size_t)b * NPTS * STRIDE;

  // ---- phase 0: counting sort by Morton cell (order within cell arbitrary;
  //      affects only grouping quality, never values/selection) ----
  for (int i = t; i < 512; i += T) hist[i] = 0;
  __syncthreads();
  int myCell[PPG];
  for (int j = 0; j < PPG; ++j) {
    int g = t * PPG + j;
    float x = Pb[(size_t)g * STRIDE];
    float y = Pb[(size_t)g * STRIDE + 1];
    float z = Pb[(size_t)g * STRIDE + 2];
    int ix = (int)(x * 8.0f); ix = ix < 0 ? 0 : (ix > 7 ? 7 : ix);
    int iy = (int)(y * 8.0f); iy = iy < 0 ? 0 : (iy > 7 ? 7 : iy);
    int iz = (int)(z * 8.0f); iz = iz < 0 ? 0 : (iz > 7 ? 7 : iz);
    // 9-bit Morton: wave (top 3 bits) = one 4x4x4 octant block of cells
    int m = ((ix & 1) << 2) | ((iy & 1) << 1) | (iz & 1)
          | (((ix >> 1) & 1) << 5) | (((iy >> 1) & 1) << 4) | (((iz >> 1) & 1) << 3)
          | (((ix >> 2) & 1) << 8) | (((iy >> 2) & 1) << 7) | (((iz >> 2) & 1) << 6);
    myCell[j] = m;
    atomicAdd(&hist[m], 1);
  }
  __syncthreads();
  {  // exclusive scan of 512 bins (1 per thread)
    int h = hist[t];
    int inc = h;
    for (int d = 1; d < 64; d <<= 1) {
      int u = __shfl_up(inc, d);
      if (lane >= d) inc += u;
    }
    if (lane == 63) wsum[wv] = inc;
    __syncthreads();
    int off = 0;
#pragma unroll
    for (int w = 0; w < NW; ++w) if (w < wv) off += wsum[w];
    base_[t] = off + inc - h;
  }
  __syncthreads();
  for (int j = 0; j < PPG; ++j) {
    int slot = atomicAdd(&base_[myCell[j]], 1);
    perm[slot] = t * PPG + j;
  }
  __syncthreads();

  // ---- phase 1: load my group into REGISTERS (coords + key-low), build bound ----
  float px[PPG], py[PPG], pz[PPG], dist[PPG];
  unsigned klo[PPG];
  float mnx = 1e30f, mny = 1e30f, mnz = 1e30f;
  float mxx = -1e30f, mxy = -1e30f, mxz = -1e30f;
#pragma unroll
  for (int j = 0; j < PPG; ++j) {
    int g = perm[t * PPG + j];
    float x = Pb[(size_t)g * STRIDE];
    float y = Pb[(size_t)g * STRIDE + 1];
    float z = Pb[(size_t)g * STRIDE + 2];
    px[j] = x; py[j] = y; pz[j] = z; dist[j] = 1e10f;
    klo[j] = 0xFFFFFFFFu - (unsigned)g;
    mnx = fminf(mnx, x); mxx = fmaxf(mxx, x);
    mny = fminf(mny, y); mxy = fmaxf(mxy, y);
    mnz = fminf(mnz, z); mxz = fmaxf(mxz, z);
  }
  double bcx = 0.5 * ((double)mnx + (double)mxx);
  double bcy = 0.5 * ((double)mny + (double)mxy);
  double bcz = 0.5 * ((double)mnz + (double)mxz);
  double r2m = 0.0;
#pragma unroll
  for (int j = 0; j < PPG; ++j) {
    double dx = (double)px[j] - bcx, dy = (double)py[j] - bcy, dz = (double)pz[j] - bcz;
    double dd = fma(dx, dx, fma(dy, dy, dz * dz));
    r2m = fmax(r2m, dd);
  }
  const double r = sqrt(r2m) * (1.0 + 1e-12) + 1e-300;   // upper bound of group radius

  // ---- initial centroid = original point 0; emit idx[0] ----
  if (t == 0) {
    float x0 = Pb[0], y0 = Pb[1], z0 = Pb[2];
    wc4[1][0] = make_float4(x0, y0, z0, 0.0f);
    size_t o = (size_t)b * NPT * 3;
    out_xyz[o] = x0; out_xyz[o + 1] = y0; out_xyz[o + 2] = z0;
    if (out_f) { out_f[o] = x0; out_f[o + 1] = y0; out_f[o + 2] = z0; }
  }
  __syncthreads();
  float ccx = wc4[1][0].x, ccy = wc4[1][0].y, ccz = wc4[1][0].z;

  unsigned long long gkey = 0;          // (dist_bits<<32) | (0xFFFFFFFF - origidx)
  float gbx = 0.0f, gby = 0.0f, gbz = 0.0f;
  double rs2 = 1e300;                   // forces rescan at s=0 (dist=1e10 everywhere)
  bool iswin = false;                   // cached: am I my wave's winner lane?

  for (int s = 0; s < NPT - 1; ++s) {
    const int p = s & 1;
    // conservative skip test: skip only if every member provably satisfies
    // d32(c,point) >= dist[point].
    double dxc = (double)ccx - bcx, dyc = (double)ccy - bcy, dzc = (double)ccz - bcz;
    double tD = fma(dxc, dxc, fma(dyc, dyc, dzc * dzc));
    bool active = (tD < rs2);
    if (active) {
      unsigned long long nk = 0;
      float nbx = 0.0f, nby = 0.0f, nbz = 0.0f;
      {
#pragma clang fp contract(off)
#pragma unroll
        for (int j = 0; j < PPG; ++j) {
          float dx = px[j] - ccx, dy = py[j] - ccy, dz = pz[j] - ccz;
          float d = (dx * dx + dy * dy) + dz * dz;     // exact np order, no FMA
          float dj = fminf(dist[j], d);
          dist[j] = dj;
          unsigned long long kj = ((unsigned long long)__float_as_uint(dj) << 32)
                                | (unsigned long long)klo[j];
          if (kj > nk) { nk = kj; nbx = px[j]; nby = py[j]; nbz = pz[j]; }
        }
      }
      gkey = nk; gbx = nbx; gby = nby; gbz = nbz;
      float gmaxf = __uint_as_float((unsigned)(gkey >> 32));
      double sg = sqrt((double)gmaxf * 1.000002 + 1e-300);
      double rr = r + sg;
      rs2 = rr * rr;
    }

    // wave max over 64-bit keys, only if some lane changed (else cached winner
    // is still the winner: all gkeys in this wave are unchanged)
    unsigned long long mb = __ballot(active);
    if (mb != 0ull) {
      unsigned long long wk = gkey;
#define STEP64(ctrl) { \
    int lo_ = (int)(unsigned)wk, hi_ = (int)(unsigned)(wk >> 32); \
    int slo_ = __builtin_amdgcn_update_dpp(lo_, lo_, ctrl, 0xf, 0xf, false); \
    int shi_ = __builtin_amdgcn_update_dpp(hi_, hi_, ctrl, 0xf, 0xf, false); \
    unsigned long long o_ = ((unsigned long long)(unsigned)shi_ << 32) | (unsigned)slo_; \
    if (o_ > wk) wk = o_; }
      STEP64(0x111)  // row_shr:1
      STEP64(0x112)  // row_shr:2
      STEP64(0x114)  // row_shr:4
      STEP64(0x118)  // row_shr:8
      STEP64(0x142)  // row_bcast:15
      STEP64(0x143)  // row_bcast:31
#undef STEP64
      unsigned wlo = (unsigned)__builtin_amdgcn_readlane((int)(unsigned)wk, 63);
      unsigned whi = (unsigned)__builtin_amdgcn_readlane((int)(unsigned)(wk >> 32), 63);
      unsigned long long wmaxk = ((unsigned long long)whi << 32) | wlo;
      iswin = (gkey == wmaxk);           // keys globally unique -> exactly one lane
    }
    if (iswin) {                          // winner lane refreshes this parity's slot
      wkeyL[p][wv] = gkey;
      wc4[p][wv] = make_float4(gbx, gby, gbz, 0.0f);
    }
    __syncthreads();
    // block select over 8 wave winners (tree; coords ride along; broadcast reads)
    unsigned long long k0 = wkeyL[p][0], k1 = wkeyL[p][1];
    unsigned long long k2 = wkeyL[p][2], k3 = wkeyL[p][3];
    unsigned long long k4 = wkeyL[p][4], k5 = wkeyL[p][5];
    unsigned long long k6 = wkeyL[p][6], k7 = wkeyL[p][7];
    float4 c0 = wc4[p][0], c1 = wc4[p][1], c2 = wc4[p][2], c3 = wc4[p][3];
    float4 c4 = wc4[p][4], c5 = wc4[p][5], c6 = wc4[p][6], c7 = wc4[p][7];
    if (k1 > k0) { k0 = k1; c0 = c1; }
    if (k3 > k2) { k2 = k3; c2 = c3; }
    if (k5 > k4) { k4 = k5; c4 = c5; }
    if (k7 > k6) { k6 = k7; c6 = c7; }
    if (k2 > k0) { k0 = k2; c0 = c2; }
    if (k6 > k4) { k4 = k6; c4 = c6; }
    if (k4 > k0) { k0 = k4; c0 = c4; }
    ccx = c0.x; ccy = c0.y; ccz = c0.z;
    if (t == 0) {
      size_t o = ((size_t)b * NPT + s + 1) * 3;
      out_xyz[o] = ccx; out_xyz[o + 1] = ccy; out_xyz[o + 2] = ccz;
      if (out_f) { out_f[o] = ccx; out_f[o + 1] = ccy; out_f[o + 2] = ccz; }
    }
  }
}

// ---------- layer-1 (fp64 compute, fp32 inputs): ball (first 32 asc) + conv ----------
template<bool APPLY>
__global__ __launch_bounds__(256) void ball1_k(
    const float* __restrict__ xyz, const float* __restrict__ l1xyz,
    const float* __restrict__ w1, const float* __restrict__ b1,
    const double* __restrict__ A1, const double* __restrict__ B1,
    float* __restrict__ l1pts,
    double* __restrict__ S1R, double* __restrict__ S2R) {
  const int blk = blockIdx.x;
  const int b = blk >> 11, s = blk & 2047;
  const int t = threadIdx.x;
  __shared__ double w1s[768];
  __shared__ double b1s[128];
  __shared__ unsigned long long wm[4];
  __shared__ int lst[32];
  __shared__ double fls[32][6];
  __shared__ double red0[128], red1[128];

  for (int i = t; i < 768; i += 256) w1s[i] = (double)w1[i];
  if (t < 128) b1s[t] = (double)b1[t];

  const float* xb = xyz + (size_t)b * 8192 * 6;
  size_t co = ((size_t)b * 2048 + s) * 3;
  double cx = (double)l1xyz[co], cy = (double)l1xyz[co+1], cz = (double)l1xyz[co+2];

  const double R2 = 0.0025 * 0.0025;
  int cnt = 0;
  const int wvv = t >> 6, lane = t & 63;
  {
#pragma clang fp contract(off)
    double cs2 = (cx*cx + cy*cy) + cz*cz;
    for (int chunk = 0; chunk < 32 && cnt < 32; ++chunk) {
      int g = chunk * 256 + t;
      double x = (double)xb[(size_t)g*6];
      double y = (double)xb[(size_t)g*6+1];
      double z = (double)xb[(size_t)g*6+2];
      double pn2 = (x*x + y*y) + z*z;
      double dot = (cx*x + cy*y) + cz*z;
      double dsq = (cs2 + pn2) - 2.0 * dot;    // exact ref formula/order
      bool pred = !(dsq > R2);
      unsigned long long m = __ballot(pred);
      if (lane == 0) wm[wvv] = m;
      __syncthreads();
      int pre = 0, tot = 0;
      for (int w = 0; w < 4; ++w) {
        int c = __popcll(wm[w]);
        if (w < wvv) pre += c;
        tot += c;
      }
      if (pred) {
        int rank = cnt + pre + __popcll(m & ((1ull << lane) - 1ull));
        if (rank < 32) lst[rank] = g;
      }
      cnt += tot;
      __syncthreads();
    }
  }
  int cc = cnt < 32 ? cnt : 32;
  if (t >= cc && t < 32) lst[t] = lst[0];   // pad with first (center in own ball)
  __syncthreads();
  if (t < 32) {
    int j = lst[t];
    fls[t][0] = (double)xb[(size_t)j*6]   - cx;
    fls[t][1] = (double)xb[(size_t)j*6+1] - cy;
    fls[t][2] = (double)xb[(size_t)j*6+2] - cz;
    fls[t][3] = (double)xb[(size_t)j*6+3];
    fls[t][4] = (double)xb[(size_t)j*6+4];
    fls[t][5] = (double)xb[(size_t)j*6+5];
  }
  __syncthreads();
  const int d = t & 127, kh = t >> 7;
  if (APPLY) {
    double a = A1[d], bb = B1[d];
    double vmax = -1e300;
    for (int k = kh; k < 32; k += 2) {
      double h = b1s[d];
#pragma unroll
      for (int c = 0; c < 6; ++c) h = fma(fls[k][c], w1s[c*128 + d], h);
      vmax = fmax(vmax, fma(a, h, bb));
    }
    if (kh == 1) red0[d] = vmax;
    __syncthreads();
    if (kh == 0) {
      double v = fmax(vmax, red0[d]);
      l1pts[((size_t)b * 2048 + s) * 128 + d] = (float)fmax(v, 0.0);
    }
  } else {
    double p1 = 0.0, p2 = 0.0;
    for (int k = kh; k < 32; k += 2) {
      double h = b1s[d];
#pragma unroll
      for (int c = 0; c < 6; ++c) h = fma(fls[k][c], w1s[c*128 + d], h);
      p1 += h; p2 = fma(h, h, p2);
    }
    if (kh == 1) { red0[d] = p1; red1[d] = p2; }
    __syncthreads();
    if (kh == 0) {
      int rep = blk & 7;
      atomicAdd(&S1R[(size_t)rep * 128 + d], p1 + red0[d]);
      atomicAdd(&S2R[(size_t)rep * 128 + d], p2 + red1[d]);
    }
  }
}

// ---------- BN finalize (fp64): A=g/sqrt(var+eps), B=be-mu*A ----------
__global__ __launch_bounds__(256) void bn_finalize(const double* __restrict__ S1,
                                                   const double* __restrict__ S2,
                                                   int nrep, int D, double invN,
                                                   const float* __restrict__ g,
                                                   const float* __restrict__ be,
                                                   double* __restrict__ A, double* __restrict__ Bc) {
  int d = blockIdx.x * 256 + threadIdx.x;
  if (d >= D) return;
  double s1 = 0.0, s2 = 0.0;
  for (int r = 0; r < nrep; ++r) {
    s1 += S1[(size_t)r * D + d];
    s2 += S2[(size_t)r * D + d];
  }
  double mu = s1 * invN;
  double var = s2 * invN - mu * mu;
  double a = (double)g[d] / sqrt(var + 1e-5);
  A[d]  = a;
  Bc[d] = (double)be[d] - mu * a;
}

// ---------- layer-2 (fp64): ball (first 16 asc) + conv(131->693); stats / apply ----------
template<bool APPLY>
__global__ __launch_bounds__(256) void ball2_k(
    const float* __restrict__ l1xyz, const float* __restrict__ l1pts,
    const float* __restrict__ l2xyz,
    const float* __restrict__ w2, const float* __restrict__ b2,
    const double* __restrict__ A2, const double* __restrict__ B2,
    float* __restrict__ outp,
    double* __restrict__ T1R, double* __restrict__ T2R) {
  const int blk = blockIdx.x;
  const int b = blk >> 8, s = blk & 255;
  const int t = threadIdx.x;
  __shared__ double fT[131][16];
  __shared__ unsigned long long wm[4];
  __shared__ int lst[16];
  const float* Pb = l1xyz + (size_t)b * 2048 * 3;
  size_t co = ((size_t)b * 256 + s) * 3;
  double cx = (double)l2xyz[co], cy = (double)l2xyz[co+1], cz = (double)l2xyz[co+2];
  const double R2 = 0.005 * 0.005;
  int cnt = 0;
  const int wvv = t >> 6, lane = t & 63;
  {
#pragma clang fp contract(off)
    double cs2 = (cx*cx + cy*cy) + cz*cz;
    for (int chunk = 0; chunk < 8 && cnt < 16; ++chunk) {
      int g = chunk * 256 + t;
      double x = (double)Pb[(size_t)g*3];
      double y = (double)Pb[(size_t)g*3+1];
      double z = (double)Pb[(size_t)g*3+2];
      double pn2 = (x*x + y*y) + z*z;
      double dot = (cx*x + cy*y) + cz*z;
      double dsq = (cs2 + pn2) - 2.0 * dot;
      bool pred = !(dsq > R2);
      unsigned long long m = __ballot(pred);
      if (lane == 0) wm[wvv] = m;
      __syncthreads();
      int pre = 0, tot = 0;
      for (int w = 0; w < 4; ++w) {
        int c = __popcll(wm[w]);
        if (w < wvv) pre += c;
        tot += c;
      }
      if (pred) {
        int rank = cnt + pre + __popcll(m & ((1ull << lane) - 1ull));
        if (rank < 16) lst[rank] = g;
      }
      cnt += tot;
      __syncthreads();
    }
  }
  int cc = cnt < 16 ? cnt : 16;
  if (t >= cc && t < 16) lst[t] = lst[0];
  __syncthreads();
  for (int i = t; i < 16 * 131; i += 256) {
    int k = i & 15, c = i >> 4;
    int j = lst[k];
    double v;
    if (c == 0)      v = (double)Pb[(size_t)j*3]   - cx;
    else if (c == 1) v = (double)Pb[(size_t)j*3+1] - cy;
    else if (c == 2) v = (double)Pb[(size_t)j*3+2] - cz;
    else             v = (double)l1pts[((size_t)b*2048 + j)*128 + (c-3)];
    fT[c][k] = v;
  }
  __syncthreads();
  const int rep = blk & 7;
  for (int dd = 0; dd < 3; ++dd) {
    int d = t + dd * 256;
    if (d >= 693) break;
    double acc[16];
    double bv = (double)b2[d];
#pragma unroll
    for (int k = 0; k < 16; ++k) acc[k] = bv;
    for (int c = 0; c < 131; ++c) {
      double wv2 = (double)w2[(size_t)c * 693 + d];
#pragma unroll
      for (int k = 0; k < 16; ++k) acc[k] = fma(fT[c][k], wv2, acc[k]);
    }
    if (APPLY) {
      double a = A2[d], bb = B2[d];
      double vmax = -1e300;
#pragma unroll
      for (int k = 0; k < 16; ++k) vmax = fmax(vmax, fma(a, acc[k], bb));
      outp[((size_t)b * 256 + s) * 693 + d] = (float)fmax(vmax, 0.0);
    } else {
      double p1 = 0.0, p2 = 0.0;
#pragma unroll
      for (int k = 0; k < 16; ++k) { p1 += acc[k]; p2 = fma(acc[k], acc[k], p2); }
      atomicAdd(&T1R[(size_t)rep * 693 + d], p1);
      atomicAdd(&T2R[(size_t)rep * 693 + d], p2);
    }
  }
}

extern "C" void kernel_launch(void* const* d_in, const int* in_sizes, int n_in,
                              void* d_out, int out_size, void* d_ws, size_t ws_size,
                              hipStream_t stream) {
  (void)out_size;
  float* out = (float*)d_out;   // fp32 outputs (reference returns float32)

  const int want[9] = {196608, 768, 128, 128, 128, 90783, 693, 693, 693};
  bool ok = (n_in == 9);
  for (int i = 0; ok && i < 9; ++i) ok = (in_sizes[i] == want[i]);
  const size_t REQ = 4600000;   // footprint ~4.42 MB
  if (!ok || ws_size < REQ) {
    sentinel_k<<<1, 1, 0, stream>>>(out);
    return;
  }

  const float* xyz = (const float*)d_in[0];
  const float* w1  = (const float*)d_in[1];
  const float* b1  = (const float*)d_in[2];
  const float* g1  = (const float*)d_in[3];
  const float* be1 = (const float*)d_in[4];
  const float* w2  = (const float*)d_in[5];
  const float* b2  = (const float*)d_in[6];
  const float* g2  = (const float*)d_in[7];
  const float* be2 = (const float*)d_in[8];

  // ---- workspace carve (doubles first) ----
  double* S1R = (double*)d_ws;            // 8*128 = 1024
  double* S2R = S1R + 1024;               // 1024
  double* T1R = S2R + 1024;               // 8*693 = 5544
  double* T2R = T1R + 5544;               // 5544
  double* A1  = T2R + 5544;               // 128
  double* B1  = A1 + 128;                 // 128
  double* A2  = B1 + 128;                 // 693
  double* B2  = A2 + 693;                 // 693
  float* l1xyz = (float*)(B2 + 693);      // 4*2048*3 = 24576 f
  float* l2xyz = l1xyz + 24576;           // 4*256*3  = 3072 f
  float* l1pts = l2xyz + 3072;            // 4*2048*128 = 4 MB

  zero_k<<<52, 256, 0, stream>>>(S1R, 13136);

  // FPS in fp32 with exact spatial pruning (selections bit-identical to the
  // dense scan; skip test is provably conservative). All per-point state in
  // registers -> zero LDS traffic in the rescan loop.
  fps_quick_k<16, 2048, 8192, 6><<<4, 512, 0, stream>>>(xyz, l1xyz, nullptr);
  fps_quick_k<4, 256, 2048, 3><<<4, 512, 0, stream>>>(l1xyz, l2xyz, out);

  ball1_k<false><<<8192, 256, 0, stream>>>(xyz, l1xyz, w1, b1, nullptr, nullptr,
                                           nullptr, S1R, S2R);
  bn_finalize<<<1, 256, 0, stream>>>(S1R, S2R, 8, 128, 1.0 / (8192.0 * 32.0), g1, be1, A1, B1);
  ball1_k<true><<<8192, 256, 0, stream>>>(xyz, l1xyz, w1, b1, A1, B1,
                                          l1pts, S1R, S2R);

  ball2_k<false><<<1024, 256, 0, stream>>>(l1xyz, l1pts, l2xyz, w2, b2, nullptr, nullptr,
                                           nullptr, T1R, T2R);
  bn_finalize<<<3, 256, 0, stream>>>(T1R, T2R, 8, 693, 1.0 / (1024.0 * 16.0), g2, be2, A2, B2);
  ball2_k<true><<<1024, 256, 0, stream>>>(l1xyz, l1pts, l2xyz, w2, b2, A2, B2,
                                          out + 3072, T1R, T2R);
}